// Round 17
// baseline (820.654 us; speedup 1.0000x reference)
//
#include <hip/hip_runtime.h>

#ifndef BATCH
#define BATCH 16
#endif

typedef float f32x2 __attribute__((ext_vector_type(2)));
__device__ __forceinline__ f32x2 mk2(float a, float b) { f32x2 r; r.x = a; r.y = b; return r; }

// ---- DPP wave64 reduction helpers (row_shr scan + row_bcast merge) --------
template<int CTRL>
__device__ __forceinline__ float dppmaxf(float v)
{
    const int d = __builtin_amdgcn_update_dpp(__float_as_int(v), __float_as_int(v),
                                              CTRL, 0xf, 0xf, false);
    return fmaxf(v, __int_as_float(d));
}
template<int CTRL>
__device__ __forceinline__ unsigned dppminu(unsigned v)
{
    const unsigned d = (unsigned)__builtin_amdgcn_update_dpp((int)v, (int)v,
                                                             CTRL, 0xf, 0xf, false);
    return (d < v) ? d : v;
}
__device__ __forceinline__ float wave_max_bcast(float v)
{
    v = dppmaxf<0x111>(v);
    v = dppmaxf<0x112>(v);
    v = dppmaxf<0x114>(v);
    v = dppmaxf<0x118>(v);
    v = dppmaxf<0x142>(v);
    v = dppmaxf<0x143>(v);
    return __int_as_float(__builtin_amdgcn_readlane(__float_as_int(v), 63));
}
__device__ __forceinline__ unsigned wave_min_bcast(unsigned v)
{
    v = dppminu<0x111>(v);
    v = dppminu<0x112>(v);
    v = dppminu<0x114>(v);
    v = dppminu<0x118>(v);
    v = dppminu<0x142>(v);
    v = dppminu<0x143>(v);
    return (unsigned)__builtin_amdgcn_readlane((int)v, 63);
}

// ---- transpose body: W[O][C] -> Wt[C][O], flat index space ----------------
__device__ __forceinline__ void transpose_body(int blk, int tid,
    const float* __restrict__ s0, float* __restrict__ d0,
    const float* __restrict__ s1, float* __restrict__ d1,
    const float* __restrict__ s2, float* __restrict__ d2,
    const float* __restrict__ s3, float* __restrict__ d3,
    const float* __restrict__ s4, float* __restrict__ d4,
    const float* __restrict__ s5, float* __restrict__ d5,
    const float* __restrict__ s6, float* __restrict__ d6,
    const float* __restrict__ s7, float* __restrict__ d7,
    const float* __restrict__ s8, float* __restrict__ d8)
{
    int i = blk * 256 + tid;
    if (i < 192)    { d0[(i%3)  *64   + i/3  ] = s0[i]; return; }  i -= 192;
    if (i < 4096)   { d1[(i&63) *64   + (i>>6)] = s1[i]; return; } i -= 4096;
    if (i < 8192)   { d2[(i&63) *128  + (i>>6)] = s2[i]; return; } i -= 8192;
    if (i < 16768)  { d3[(i%131)*128  + i/131] = s3[i]; return; }  i -= 16768;
    if (i < 16384)  { d4[(i&127)*128  + (i>>7)] = s4[i]; return; } i -= 16384;
    if (i < 32768)  { d5[(i&127)*256  + (i>>7)] = s5[i]; return; } i -= 32768;
    if (i < 66304)  { d6[(i%259)*256  + i/259] = s6[i]; return; }  i -= 66304;
    if (i < 131072) { d7[(i&255)*512  + (i>>8)] = s7[i]; return; } i -= 131072;
    if (i < 524288) { d8[(i&511)*1024 + (i>>9)] = s8[i]; return; }
}

// ---------------------------------------------------------------------------
// FPS stage 1 only (4096 -> 512) + weight-transpose blocks. (unchanged R16)
// ---------------------------------------------------------------------------
template<int N, int NP1, int BLOCK>
__global__ __launch_bounds__(BLOCK)
void fps1_fused(const float* __restrict__ xyz, float* __restrict__ out1,
                const float* __restrict__ ts0, float* __restrict__ td0,
                const float* __restrict__ ts1, float* __restrict__ td1,
                const float* __restrict__ ts2, float* __restrict__ td2,
                const float* __restrict__ ts3, float* __restrict__ td3,
                const float* __restrict__ ts4, float* __restrict__ td4,
                const float* __restrict__ ts5, float* __restrict__ td5,
                const float* __restrict__ ts6, float* __restrict__ td6,
                const float* __restrict__ ts7, float* __restrict__ td7,
                const float* __restrict__ ts8, float* __restrict__ td8)
{
#pragma clang fp contract(off)
    if ((int)blockIdx.x >= BATCH) {
        transpose_body(blockIdx.x - BATCH, threadIdx.x,
                       ts0, td0, ts1, td1, ts2, td2, ts3, td3, ts4, td4,
                       ts5, td5, ts6, td6, ts7, td7, ts8, td8);
        return;
    }
    constexpr int P  = N / BLOCK;
    constexpr int NW = BLOCK / 64;
    __shared__ float sx[N], sy[N], sz[N];
    __shared__ float s2x[NP1], s2y[NP1], s2z[NP1];
    __shared__ unsigned long long wslot[2][NW];
    const int b = blockIdx.x, t = threadIdx.x;
    const int lane = t & 63, wv = t >> 6;
    const float* xb = xyz + (size_t)b * N * 3;
    float px[P], py[P], pz[P], dist[P];
#pragma unroll
    for (int j = 0; j < P; ++j) {
        const int i = t + j * BLOCK;
        const float x = xb[i*3+0], y = xb[i*3+1], z = xb[i*3+2];
        sx[i] = x; sy[i] = y; sz[i] = z;
        px[j] = x; py[j] = y; pz[j] = z;
        dist[j] = 1e10f;
    }
    __syncthreads();
    float fx = sx[0], fy = sy[0], fz = sz[0];
    if (t == 0) { s2x[0] = fx; s2y[0] = fy; s2z[0] = fz; }
    for (int s = 1; s < NP1; ++s) {
        float bestv = -1.f; int besti = 0;
#pragma unroll
        for (int j = 0; j < P; ++j) {
            const float dx = px[j]-fx, dy = py[j]-fy, dz = pz[j]-fz;
            const float d = (dx*dx + dy*dy) + dz*dz;
            const float nd = fminf(dist[j], d);
            dist[j] = nd;
            if (nd > bestv) { bestv = nd; besti = t + j * BLOCK; }
        }
        const float wm = wave_max_bcast(bestv);
        const unsigned cand = (bestv == wm) ? (unsigned)besti : 0xffffffffu;
        const unsigned wi = wave_min_bcast(cand);
        const int par = s & 1;
        if (lane == 0)
            wslot[par][wv] = ((unsigned long long)__float_as_uint(wm) << 32)
                           | (unsigned)(~wi);
        __syncthreads();
        unsigned long long pa = wslot[par][0];
#pragma unroll
        for (int w = 1; w < NW; ++w) {
            const unsigned long long pb = wslot[par][w];
            pa = (pb > pa) ? pb : pa;
        }
        const int far = (int)(~(unsigned)pa);
        fx = sx[far]; fy = sy[far]; fz = sz[far];
        if (t == 0) { s2x[s] = fx; s2y[s] = fy; s2z[s] = fz; }
    }
    __syncthreads();
    for (int i = t; i < NP1; i += BLOCK) {
        out1[((size_t)b*NP1 + i)*3 + 0] = s2x[i];
        out1[((size_t)b*NP1 + i)*3 + 1] = s2y[i];
        out1[((size_t)b*NP1 + i)*3 + 2] = s2z[i];
    }
}

// ---- inline ball-query scan: ONE wave scans one query, indices -> LDS -----
template<int N, int K>
__device__ __forceinline__ void ballq_scan_lds(const float* __restrict__ xb,
                                               const float qx, const float qy,
                                               const float qz, const float r2,
                                               int* __restrict__ sidx,
                                               const int lane)
{
#pragma clang fp contract(off)
    int base = 0, first = -1;
    for (int c = 0; c < N; c += 64) {
        const int i = c + lane;
        const float dx = xb[i*3+0]-qx, dy = xb[i*3+1]-qy, dz = xb[i*3+2]-qz;
        const float d = (dx*dx + dy*dy) + dz*dz;
        const bool hit = !(d > r2);
        const unsigned long long m = __ballot(hit);
        if (first < 0 && m) first = c + __builtin_ctzll(m);
        const int pos = base + __popcll(m & ((1ull << lane) - 1ull));
        if (hit && pos < K) sidx[pos] = i;
        base += __popcll(m);
        if (base >= K) break;
    }
    if (base < K && lane >= base && lane < K) sidx[lane] = first;
}

// 8 packed FMAs against 16 contiguous transposed weights (bit-identical).
__device__ __forceinline__ void fma16pk(f32x2 (&acc)[8], const float f,
                                        const float* __restrict__ wrow)
{
    const float4 w0 = ((const float4*)wrow)[0];
    const float4 w1 = ((const float4*)wrow)[1];
    const float4 w2 = ((const float4*)wrow)[2];
    const float4 w3 = ((const float4*)wrow)[3];
    const f32x2 ff = mk2(f, f);
    acc[0] += ff * mk2(w0.x, w0.y);
    acc[1] += ff * mk2(w0.z, w0.w);
    acc[2] += ff * mk2(w1.x, w1.y);
    acc[3] += ff * mk2(w1.z, w1.w);
    acc[4] += ff * mk2(w2.x, w2.y);
    acc[5] += ff * mk2(w2.z, w2.w);
    acc[6] += ff * mk2(w3.x, w3.y);
    acc[7] += ff * mk2(w3.z, w3.w);
}

__device__ __forceinline__ float pool_half(float v)
{
    v = fmaxf(v, __shfl_xor(v, 1));
    v = fmaxf(v, __shfl_xor(v, 2));
    v = fmaxf(v, __shfl_xor(v, 4));
    v = fmaxf(v, __shfl_xor(v, 8));
    v = fmaxf(v, __shfl_xor(v, 16));
    return v;
}
__device__ __forceinline__ float pool_full(float v)
{
    v = pool_half(v);
    return fmaxf(v, __shfl_xor(v, 32));
}

// ---------------------------------------------------------------------------
// K2: blocks [0,BATCH) run FPS stage 2 with a SINGLE WAVE (512 pts, 8/lane
// blocked ownership) -- no barriers, no cross-wave exchange; per-step chain
// = 8-pt update + DPP max + min-index reduce + same-wave LDS coord
// broadcast. Blocked ownership keeps first-index tie-break exact (per-lane
// strict > keeps lowest j; min besti across lanes = global first index).
// Blocks [BATCH,...) run SA1 (+inline ball query), unchanged.
// ---------------------------------------------------------------------------
template<int NP1, int NP2, int BLOCK>
__global__ __launch_bounds__(BLOCK)
void fps2_sa1(const float* __restrict__ xyz, const float* __restrict__ l1xyz,
              float* __restrict__ out2, const float r2,
              const float* __restrict__ Wt0, const float* __restrict__ B0,
              const float* __restrict__ Wt1, const float* __restrict__ B1,
              const float* __restrict__ Wt2, const float* __restrict__ B2,
              float* __restrict__ out)
{
#pragma clang fp contract(off)
    __shared__ __align__(16) char smem[16640];
    const int tid = threadIdx.x, lane = tid & 63;
    if ((int)blockIdx.x < BATCH) {
        if (tid >= 64) return;                     // single wave does stage 2
        constexpr int P2 = NP1 / 64;               // 8 pts per lane (blocked)
        float* s2x = (float*)smem;                 // [NP1]
        float* s2y = s2x + NP1;
        float* s2z = s2y + NP1;
        float* o2x = s2z + NP1;                    // [NP2]
        float* o2y = o2x + NP2;
        float* o2z = o2y + NP2;
        const int b = blockIdx.x;
        const float* l1b = l1xyz + (size_t)b * NP1 * 3;
        float px[P2], py[P2], pz[P2], dist[P2];
#pragma unroll
        for (int j = 0; j < P2; ++j) {
            const int i = lane * P2 + j;
            const float x = l1b[i*3+0], y = l1b[i*3+1], z = l1b[i*3+2];
            s2x[i] = x; s2y[i] = y; s2z[i] = z;
            px[j] = x; py[j] = y; pz[j] = z;
            dist[j] = 1e10f;
        }
        float fx = l1b[0], fy = l1b[1], fz = l1b[2];
        if (lane == 0) { o2x[0] = fx; o2y[0] = fy; o2z[0] = fz; }
        for (int s = 1; s < NP2; ++s) {
            float bestv = -1.f; int besti = 0;
#pragma unroll
            for (int j = 0; j < P2; ++j) {
                const float dx = px[j]-fx, dy = py[j]-fy, dz = pz[j]-fz;
                const float d = (dx*dx + dy*dy) + dz*dz;
                const float nd = fminf(dist[j], d);
                dist[j] = nd;
                if (nd > bestv) { bestv = nd; besti = lane * P2 + j; }
            }
            const float wm = wave_max_bcast(bestv);
            const unsigned cand = (bestv == wm) ? (unsigned)besti : 0xffffffffu;
            const unsigned wi = wave_min_bcast(cand);
            fx = s2x[wi]; fy = s2y[wi]; fz = s2z[wi];   // same-wave LDS broadcast
            if (lane == 0) { o2x[s] = fx; o2y[s] = fy; o2z[s] = fz; }
        }
        for (int i = lane; i < NP2; i += 64) {
            out2[((size_t)b*NP2 + i)*3 + 0] = o2x[i];
            out2[((size_t)b*NP2 + i)*3 + 1] = o2y[i];
            out2[((size_t)b*NP2 + i)*3 + 2] = o2z[i];
        }
        return;
    }
    // ---------------- SA1 (+inline ball query), unchanged ----------------
    float (*buf)[64] = (float(*)[64])smem;         // [64][64]
    int* sidx = (int*)(smem + 16384);              // [64]
    const int wave = __builtin_amdgcn_readfirstlane(tid >> 6);
    const int row0 = (blockIdx.x - BATCH) * 64;
    const int g0 = row0 >> 5;
    const int b = g0 >> 9;
    const float* xb = xyz + (size_t)b * 4096 * 3;
    if (wave < 2) {
        const int g = g0 + wave;
        ballq_scan_lds<4096, 32>(xb,
            l1xyz[(size_t)g*3 + 0], l1xyz[(size_t)g*3 + 1], l1xyz[(size_t)g*3 + 2],
            r2, sidx + wave*32, lane);
    }
    __syncthreads();
    const int g = g0 + (lane >> 5);
    const int i = sidx[lane];
    const float* p = xb + (size_t)i * 3;
    const float f0 = p[0] - l1xyz[(size_t)g*3 + 0];
    const float f1 = p[1] - l1xyz[(size_t)g*3 + 1];
    const float f2 = p[2] - l1xyz[(size_t)g*3 + 2];
    const int oc0 = wave * 16;
    f32x2 aL[8], aH[8];
#pragma unroll
    for (int j = 0; j < 16; ++j) {
        const float v = B0[oc0+j] + f0*Wt0[0*64+oc0+j] + f1*Wt0[1*64+oc0+j] + f2*Wt0[2*64+oc0+j];
        buf[oc0+j][lane] = fmaxf(v, 0.f);
    }
    __syncthreads();
#pragma unroll
    for (int k = 0; k < 8; ++k) aL[k] = mk2(B1[oc0+2*k], B1[oc0+2*k+1]);
#pragma unroll 4
    for (int ci = 0; ci < 64; ++ci)
        fma16pk(aL, buf[ci][lane], Wt1 + ci*64 + oc0);
    __syncthreads();
#pragma unroll
    for (int k = 0; k < 8; ++k) {
        buf[oc0+2*k][lane]   = fmaxf(aL[k].x, 0.f);
        buf[oc0+2*k+1][lane] = fmaxf(aL[k].y, 0.f);
    }
    __syncthreads();
#pragma unroll
    for (int k = 0; k < 8; ++k) {
        aL[k] = mk2(B2[oc0+2*k], B2[oc0+2*k+1]);
        aH[k] = mk2(B2[64+oc0+2*k], B2[64+oc0+2*k+1]);
    }
#pragma unroll 2
    for (int ci = 0; ci < 64; ++ci) {
        const float f = buf[ci][lane];
        fma16pk(aL, f, Wt2 + ci*128 + oc0);
        fma16pk(aH, f, Wt2 + ci*128 + 64 + oc0);
    }
#pragma unroll
    for (int k = 0; k < 8; ++k) {
        const float v0 = pool_half(fmaxf(aL[k].x, 0.f));
        const float v1 = pool_half(fmaxf(aL[k].y, 0.f));
        const float w0 = pool_half(fmaxf(aH[k].x, 0.f));
        const float w1 = pool_half(fmaxf(aH[k].y, 0.f));
        if ((lane & 31) == 0) {
            const size_t orow = (size_t)((row0 + lane) >> 5) * 128;
            out[orow + oc0 + 2*k]       = v0;
            out[orow + oc0 + 2*k + 1]   = v1;
            out[orow + 64 + oc0 + 2*k]     = w0;
            out[orow + 64 + oc0 + 2*k + 1] = w1;
        }
    }
}

// ---------------------------------------------------------------------------
// SA2 fused + inline ball query + SA3-L1 + SA3-L2 epilogues. (unchanged R15)
// ---------------------------------------------------------------------------
__global__ __launch_bounds__(256)
void sa2_fused(const float* __restrict__ l1xyz, const float* __restrict__ l1pts,
               const float* __restrict__ nxyz, const float r2,
               const float* __restrict__ Wt0, const float* __restrict__ B0,
               const float* __restrict__ Wt1, const float* __restrict__ B1,
               const float* __restrict__ Wt2, const float* __restrict__ B2,
               const float* __restrict__ Wt30, const float* __restrict__ B30,
               const float* __restrict__ Wt31, const float* __restrict__ B31,
               float* __restrict__ outH2)
{
    __shared__ float buf[128][64];
    __shared__ float pool[256];
    __shared__ float h1s[256];
    __shared__ int sidx[64];
    const int tid = threadIdx.x, lane = tid & 63;
    const int wave = __builtin_amdgcn_readfirstlane(tid >> 6);
    const int gblk = blockIdx.x;
    const int b = gblk >> 7;
    const float cx = nxyz[(size_t)gblk*3 + 0];
    const float cy = nxyz[(size_t)gblk*3 + 1];
    const float cz = nxyz[(size_t)gblk*3 + 2];
    const float* xb = l1xyz + (size_t)b * 512 * 3;
    if (wave == 0)
        ballq_scan_lds<512, 64>(xb, cx, cy, cz, r2, sidx, lane);
    __syncthreads();
    const int myi = sidx[lane];
    const float* pc = xb + (size_t)myi * 3;
    const float f0 = pc[0] - cx;
    const float f1 = pc[1] - cy;
    const float f2 = pc[2] - cz;
    for (int r = wave; r < 64; r += 4) {
        const int i2 = sidx[r];
        const float* src = l1pts + ((size_t)b*512 + i2) * 128;
        buf[lane][r ^ lane]    = src[lane];
        buf[lane+64][r ^ lane] = src[lane + 64];
    }
    __syncthreads();
    const int oc0 = wave * 16;
    f32x2 aL[8], aH[8];
#pragma unroll
    for (int k = 0; k < 8; ++k) {
        const int j0 = oc0 + 2*k, j1 = oc0 + 2*k + 1;
        aL[k] = mk2(B0[j0]    + f0*Wt0[j0]     + f1*Wt0[128+j0]    + f2*Wt0[256+j0],
                    B0[j1]    + f0*Wt0[j1]     + f1*Wt0[128+j1]    + f2*Wt0[256+j1]);
        aH[k] = mk2(B0[64+j0] + f0*Wt0[64+j0]  + f1*Wt0[192+j0]    + f2*Wt0[320+j0],
                    B0[64+j1] + f0*Wt0[64+j1]  + f1*Wt0[192+j1]    + f2*Wt0[320+j1]);
    }
#pragma unroll 2
    for (int ci = 0; ci < 128; ++ci) {
        const float f = buf[ci][lane ^ (ci & 63)];
        const float* wp = Wt0 + (size_t)(ci+3)*128;
        fma16pk(aL, f, wp + oc0);
        fma16pk(aH, f, wp + 64 + oc0);
    }
    __syncthreads();
#pragma unroll
    for (int k = 0; k < 8; ++k) {
        buf[oc0+2*k][lane]      = fmaxf(aL[k].x, 0.f);
        buf[oc0+2*k+1][lane]    = fmaxf(aL[k].y, 0.f);
        buf[64+oc0+2*k][lane]   = fmaxf(aH[k].x, 0.f);
        buf[64+oc0+2*k+1][lane] = fmaxf(aH[k].y, 0.f);
    }
    __syncthreads();
#pragma unroll
    for (int k = 0; k < 8; ++k) {
        aL[k] = mk2(B1[oc0+2*k], B1[oc0+2*k+1]);
        aH[k] = mk2(B1[64+oc0+2*k], B1[64+oc0+2*k+1]);
    }
#pragma unroll 2
    for (int ci = 0; ci < 128; ++ci) {
        const float f = buf[ci][lane];
        const float* wp = Wt1 + (size_t)ci*128;
        fma16pk(aL, f, wp + oc0);
        fma16pk(aH, f, wp + 64 + oc0);
    }
    __syncthreads();
#pragma unroll
    for (int k = 0; k < 8; ++k) {
        buf[oc0+2*k][lane]      = fmaxf(aL[k].x, 0.f);
        buf[oc0+2*k+1][lane]    = fmaxf(aL[k].y, 0.f);
        buf[64+oc0+2*k][lane]   = fmaxf(aH[k].x, 0.f);
        buf[64+oc0+2*k+1][lane] = fmaxf(aH[k].y, 0.f);
    }
    __syncthreads();
    for (int half = 0; half < 2; ++half) {
        const int oc = half*128 + oc0;
#pragma unroll
        for (int k = 0; k < 8; ++k) {
            aL[k] = mk2(B2[oc+2*k], B2[oc+2*k+1]);
            aH[k] = mk2(B2[64+oc+2*k], B2[64+oc+2*k+1]);
        }
#pragma unroll 2
        for (int ci = 0; ci < 128; ++ci) {
            const float f = buf[ci][lane];
            const float* wp = Wt2 + (size_t)ci*256;
            fma16pk(aL, f, wp + oc);
            fma16pk(aH, f, wp + 64 + oc);
        }
#pragma unroll
        for (int k = 0; k < 8; ++k) {
            const float v0 = pool_full(fmaxf(aL[k].x, 0.f));
            const float v1 = pool_full(fmaxf(aL[k].y, 0.f));
            const float w0 = pool_full(fmaxf(aH[k].x, 0.f));
            const float w1 = pool_full(fmaxf(aH[k].y, 0.f));
            if (lane == 0) {
                pool[oc + 2*k]        = v0;
                pool[oc + 2*k + 1]    = v1;
                pool[64 + oc + 2*k]   = w0;
                pool[64 + oc + 2*k+1] = w1;
            }
        }
    }
    __syncthreads();
    {
        float acc = B30[tid] + cx*Wt30[0*256+tid] + cy*Wt30[1*256+tid] + cz*Wt30[2*256+tid];
#pragma unroll 8
        for (int ci = 0; ci < 256; ++ci)
            acc += pool[ci] * Wt30[(size_t)(ci+3)*256 + tid];
        h1s[tid] = fmaxf(acc, 0.f);
    }
    __syncthreads();
    {
        float a0 = B31[tid], a1 = B31[256 + tid];
#pragma unroll 8
        for (int ci = 0; ci < 256; ++ci) {
            const float f = h1s[ci];
            a0 += f * Wt31[(size_t)ci*512 + tid];
            a1 += f * Wt31[(size_t)ci*512 + 256 + tid];
        }
        outH2[(size_t)gblk*512 + tid]       = fmaxf(a0, 0.f);
        outH2[(size_t)gblk*512 + 256 + tid] = fmaxf(a1, 0.f);
    }
}

// ---------------------------------------------------------------------------
// SA3 GEMM layer (<512,1024,POOL>), packed-FMA accumulators. (unchanged)
// ---------------------------------------------------------------------------
template<int CIN, int COUT, bool CONCAT3, bool POOL>
__global__ __launch_bounds__(256)
void mlp_gemm_kernel(const float* __restrict__ inA, const float* __restrict__ inB,
                     const float* __restrict__ Wt, const float* __restrict__ Bb,
                     float* __restrict__ out)
{
    __shared__ float featS[128][64];
    const int tid = threadIdx.x, lane = tid & 63;
    const int wave = __builtin_amdgcn_readfirstlane(tid >> 6);
    const int row0 = blockIdx.x * 64;
    const int oc0 = blockIdx.y * 64 + wave * 16;
    f32x2 acc[8];
#pragma unroll
    for (int k = 0; k < 8; ++k) acc[k] = mk2(Bb[oc0+2*k], Bb[oc0+2*k+1]);
    for (int c0 = 0; c0 < CIN; c0 += 128) {
        const int csz = (CIN - c0 < 128) ? (CIN - c0) : 128;
        __syncthreads();
        for (int r = wave; r < 64; r += 4) {
            const int row = row0 + r;
            for (int cl = lane; cl < csz; cl += 64) {
                const int cig = c0 + cl;
                float v;
                if (CONCAT3)
                    v = (cig < 3) ? inA[(size_t)row*3 + cig]
                                  : inB[(size_t)row*(CIN-3) + (cig - 3)];
                else
                    v = inA[(size_t)row*CIN + cig];
                featS[cl][r ^ (cl & 63)] = v;
            }
        }
        __syncthreads();
        if (csz == 128) {
#pragma unroll 4
            for (int ci = 0; ci < 128; ++ci)
                fma16pk(acc, featS[ci][lane ^ (ci & 63)], Wt + (size_t)(c0+ci)*COUT + oc0);
        } else {
            for (int ci = 0; ci < csz; ++ci)
                fma16pk(acc, featS[ci][lane ^ (ci & 63)], Wt + (size_t)(c0+ci)*COUT + oc0);
        }
    }
    if (POOL) {
#pragma unroll
        for (int k = 0; k < 8; ++k) {
            const float v0 = pool_full(fmaxf(acc[k].x, 0.f));
            const float v1 = pool_full(fmaxf(acc[k].y, 0.f));
            if (lane == 0) {
                out[(size_t)blockIdx.x * COUT + oc0 + 2*k]     = v0;
                out[(size_t)blockIdx.x * COUT + oc0 + 2*k + 1] = v1;
            }
        }
    } else {
        float4 o0, o1, o2, o3;
        o0.x=fmaxf(acc[0].x,0.f); o0.y=fmaxf(acc[0].y,0.f); o0.z=fmaxf(acc[1].x,0.f); o0.w=fmaxf(acc[1].y,0.f);
        o1.x=fmaxf(acc[2].x,0.f); o1.y=fmaxf(acc[2].y,0.f); o1.z=fmaxf(acc[3].x,0.f); o1.w=fmaxf(acc[3].y,0.f);
        o2.x=fmaxf(acc[4].x,0.f); o2.y=fmaxf(acc[4].y,0.f); o2.z=fmaxf(acc[5].x,0.f); o2.w=fmaxf(acc[5].y,0.f);
        o3.x=fmaxf(acc[6].x,0.f); o3.y=fmaxf(acc[6].y,0.f); o3.z=fmaxf(acc[7].x,0.f); o3.w=fmaxf(acc[7].y,0.f);
        float4* op = (float4*)(out + (size_t)(row0 + lane)*COUT + oc0);
        op[0]=o0; op[1]=o1; op[2]=o2; op[3]=o3;
    }
}

// y[b][o] = fb[o] + max(pmax[2b], pmax[2b+1]) . fw[o]; one wave per output
__global__ __launch_bounds__(256)
void fc_kernel(const float* __restrict__ pmax, const float* __restrict__ fw,
               const float* __restrict__ fb, float* __restrict__ y)
{
    const int gw = (blockIdx.x * 256 + threadIdx.x) >> 6;
    const int lane = threadIdx.x & 63;
    const int b = gw >> 10, o = gw & 1023;
    const float4* g0 = (const float4*)(pmax + (size_t)(2*b) * 1024);
    const float4* g1 = (const float4*)(pmax + (size_t)(2*b+1) * 1024);
    const float4* wv = (const float4*)(fw + (size_t)o * 1024);
    float acc = 0.f;
#pragma unroll
    for (int r = 0; r < 4; ++r) {
        const float4 a = g0[lane + r*64];
        const float4 c = g1[lane + r*64];
        const float4 w = wv[lane + r*64];
        acc += fmaxf(a.x,c.x)*w.x + fmaxf(a.y,c.y)*w.y
             + fmaxf(a.z,c.z)*w.z + fmaxf(a.w,c.w)*w.w;
    }
#pragma unroll
    for (int m = 32; m >= 1; m >>= 1) acc += __shfl_xor(acc, m);
    if (lane == 0) y[gw] = acc + fb[o];
}

extern "C" void kernel_launch(void* const* d_in, const int* in_sizes, int n_in,
                              void* d_out, int out_size, void* d_ws, size_t ws_size,
                              hipStream_t stream)
{
    (void)in_sizes; (void)n_in; (void)out_size; (void)ws_size;
    const float* x   = (const float*)d_in[0];
    const float* s1w0 = (const float*)d_in[1];  const float* s1b0 = (const float*)d_in[2];
    const float* s1w1 = (const float*)d_in[3];  const float* s1b1 = (const float*)d_in[4];
    const float* s1w2 = (const float*)d_in[5];  const float* s1b2 = (const float*)d_in[6];
    const float* s2w0 = (const float*)d_in[7];  const float* s2b0 = (const float*)d_in[8];
    const float* s2w1 = (const float*)d_in[9];  const float* s2b1 = (const float*)d_in[10];
    const float* s2w2 = (const float*)d_in[11]; const float* s2b2 = (const float*)d_in[12];
    const float* s3w0 = (const float*)d_in[13]; const float* s3b0 = (const float*)d_in[14];
    const float* s3w1 = (const float*)d_in[15]; const float* s3b1 = (const float*)d_in[16];
    const float* s3w2 = (const float*)d_in[17]; const float* s3b2 = (const float*)d_in[18];
    const float* fw  = (const float*)d_in[19]; const float* fb  = (const float*)d_in[20];
    float* y = (float*)d_out;

    char* ws = (char*)d_ws;
    float* l1_xyz = (float*)(ws + 0);          // 16*512*3
    float* l1_pts = (float*)(ws + 1146880);    // 16*512*128
    float* l2_xyz = (float*)(ws + 5341184);    // 16*128*3
    float* h2     = (float*)(ws + 10084352);   // 2048*512
    float* pmax   = (float*)(ws + 14278656);   // 32*1024 partial maxes
    float* wt1_0  = (float*)(ws + 14409728);   // [3][64]
    float* wt1_1  = (float*)(ws + 14410496);   // [64][64]
    float* wt1_2  = (float*)(ws + 14426880);   // [64][128]
    float* wt2_0  = (float*)(ws + 14459648);   // [131][128]
    float* wt2_1  = (float*)(ws + 14526720);   // [128][128]
    float* wt2_2  = (float*)(ws + 14592256);   // [128][256]
    float* wt3_0  = (float*)(ws + 14723328);   // [259][256]
    float* wt3_1  = (float*)(ws + 14988544);   // [256][512]
    float* wt3_2  = (float*)(ws + 15512832);   // [512][1024]

    const float r2_1 = (float)(0.2 * 0.2);
    const float r2_2 = (float)(0.4 * 0.4);

    // K1: FPS stage 1 (16 blocks) + all weight transposes (3126 blocks)
    fps1_fused<4096, 512, 256><<<BATCH + 3126, 256, 0, stream>>>(
        x, l1_xyz,
        s1w0, wt1_0, s1w1, wt1_1, s1w2, wt1_2,
        s2w0, wt2_0, s2w1, wt2_1, s2w2, wt2_2,
        s3w0, wt3_0, s3w1, wt3_1, s3w2, wt3_2);
    // K2: single-wave FPS stage 2 (16 blocks) concurrent with SA1 (4096 blocks)
    fps2_sa1<512, 128, 256><<<BATCH + (BATCH*512*32)/64, 256, 0, stream>>>(
        x, l1_xyz, l2_xyz, r2_1,
        wt1_0, s1b0, wt1_1, s1b1, wt1_2, s1b2, l1_pts);
    sa2_fused<<<BATCH*128, 256, 0, stream>>>(l1_xyz, l1_pts, l2_xyz, r2_2,
        wt2_0, s2b0, wt2_1, s2b1, wt2_2, s2b2,
        wt3_0, s3b0, wt3_1, s3b1, h2);
    mlp_gemm_kernel<512, 1024, false, true ><<<dim3(32, 16), 256, 0, stream>>>(h2, nullptr, wt3_2, s3b2, pmax);
    fc_kernel<<<(BATCH*1024)/4, 256, 0, stream>>>(pmax, fw, fb, y);
}

// Round 18
// 815.029 us; speedup vs baseline: 1.0069x; 1.0069x over previous
//
#include <hip/hip_runtime.h>

#ifndef BATCH
#define BATCH 16
#endif

typedef float f32x2 __attribute__((ext_vector_type(2)));
__device__ __forceinline__ f32x2 mk2(float a, float b) { f32x2 r; r.x = a; r.y = b; return r; }

// ---- DPP wave64 reduction helpers (row_shr scan + row_bcast merge) --------
template<int CTRL>
__device__ __forceinline__ float dppmaxf(float v)
{
    const int d = __builtin_amdgcn_update_dpp(__float_as_int(v), __float_as_int(v),
                                              CTRL, 0xf, 0xf, false);
    return fmaxf(v, __int_as_float(d));
}
template<int CTRL>
__device__ __forceinline__ unsigned dppminu(unsigned v)
{
    const unsigned d = (unsigned)__builtin_amdgcn_update_dpp((int)v, (int)v,
                                                             CTRL, 0xf, 0xf, false);
    return (d < v) ? d : v;
}
__device__ __forceinline__ float wave_max_bcast(float v)
{
    v = dppmaxf<0x111>(v);
    v = dppmaxf<0x112>(v);
    v = dppmaxf<0x114>(v);
    v = dppmaxf<0x118>(v);
    v = dppmaxf<0x142>(v);
    v = dppmaxf<0x143>(v);
    return __int_as_float(__builtin_amdgcn_readlane(__float_as_int(v), 63));
}
__device__ __forceinline__ unsigned wave_min_bcast(unsigned v)
{
    v = dppminu<0x111>(v);
    v = dppminu<0x112>(v);
    v = dppminu<0x114>(v);
    v = dppminu<0x118>(v);
    v = dppminu<0x142>(v);
    v = dppminu<0x143>(v);
    return (unsigned)__builtin_amdgcn_readlane((int)v, 63);
}

// ---- transpose body: W[O][C] -> Wt[C][O], flat index space ----------------
__device__ __forceinline__ void transpose_body(int blk, int tid,
    const float* __restrict__ s0, float* __restrict__ d0,
    const float* __restrict__ s1, float* __restrict__ d1,
    const float* __restrict__ s2, float* __restrict__ d2,
    const float* __restrict__ s3, float* __restrict__ d3,
    const float* __restrict__ s4, float* __restrict__ d4,
    const float* __restrict__ s5, float* __restrict__ d5,
    const float* __restrict__ s6, float* __restrict__ d6,
    const float* __restrict__ s7, float* __restrict__ d7,
    const float* __restrict__ s8, float* __restrict__ d8)
{
    int i = blk * 256 + tid;
    if (i < 192)    { d0[(i%3)  *64   + i/3  ] = s0[i]; return; }  i -= 192;
    if (i < 4096)   { d1[(i&63) *64   + (i>>6)] = s1[i]; return; } i -= 4096;
    if (i < 8192)   { d2[(i&63) *128  + (i>>6)] = s2[i]; return; } i -= 8192;
    if (i < 16768)  { d3[(i%131)*128  + i/131] = s3[i]; return; }  i -= 16768;
    if (i < 16384)  { d4[(i&127)*128  + (i>>7)] = s4[i]; return; } i -= 16384;
    if (i < 32768)  { d5[(i&127)*256  + (i>>7)] = s5[i]; return; } i -= 32768;
    if (i < 66304)  { d6[(i%259)*256  + i/259] = s6[i]; return; }  i -= 66304;
    if (i < 131072) { d7[(i&255)*512  + (i>>8)] = s7[i]; return; } i -= 131072;
    if (i < 524288) { d8[(i&511)*1024 + (i>>9)] = s8[i]; return; }
}

// ---------------------------------------------------------------------------
// FPS stage 1 (4096 -> 512) + weight-transpose blocks.
// R17 structure; dist update now packs point PAIRS (j, j+1) of the same lane
// into f32x2 (v_pk_sub/mul/add/min). Interleaved ownership and ORDERED scalar
// first-index compares preserved -> bit-identical selection.
// ---------------------------------------------------------------------------
template<int N, int NP1, int BLOCK>
__global__ __launch_bounds__(BLOCK)
void fps1_fused(const float* __restrict__ xyz, float* __restrict__ out1,
                const float* __restrict__ ts0, float* __restrict__ td0,
                const float* __restrict__ ts1, float* __restrict__ td1,
                const float* __restrict__ ts2, float* __restrict__ td2,
                const float* __restrict__ ts3, float* __restrict__ td3,
                const float* __restrict__ ts4, float* __restrict__ td4,
                const float* __restrict__ ts5, float* __restrict__ td5,
                const float* __restrict__ ts6, float* __restrict__ td6,
                const float* __restrict__ ts7, float* __restrict__ td7,
                const float* __restrict__ ts8, float* __restrict__ td8)
{
#pragma clang fp contract(off)
    if ((int)blockIdx.x >= BATCH) {
        transpose_body(blockIdx.x - BATCH, threadIdx.x,
                       ts0, td0, ts1, td1, ts2, td2, ts3, td3, ts4, td4,
                       ts5, td5, ts6, td6, ts7, td7, ts8, td8);
        return;
    }
    constexpr int P  = N / BLOCK;      // 16
    constexpr int H  = P / 2;          // 8 packed pairs
    constexpr int NW = BLOCK / 64;
    __shared__ float sx[N], sy[N], sz[N];
    __shared__ float s2x[NP1], s2y[NP1], s2z[NP1];
    __shared__ unsigned long long wslot[2][NW];
    const int b = blockIdx.x, t = threadIdx.x;
    const int lane = t & 63, wv = t >> 6;
    const float* xb = xyz + (size_t)b * N * 3;
    f32x2 vx[H], vy[H], vz[H], vd[H];
#pragma unroll
    for (int k = 0; k < H; ++k) {
        const int i0 = t + (2*k)   * BLOCK;
        const int i1 = t + (2*k+1) * BLOCK;
        const float x0 = xb[i0*3+0], y0 = xb[i0*3+1], z0 = xb[i0*3+2];
        const float x1 = xb[i1*3+0], y1 = xb[i1*3+1], z1 = xb[i1*3+2];
        sx[i0] = x0; sy[i0] = y0; sz[i0] = z0;
        sx[i1] = x1; sy[i1] = y1; sz[i1] = z1;
        vx[k] = mk2(x0, x1); vy[k] = mk2(y0, y1); vz[k] = mk2(z0, z1);
        vd[k] = mk2(1e10f, 1e10f);
    }
    __syncthreads();
    float fx = sx[0], fy = sy[0], fz = sz[0];
    if (t == 0) { s2x[0] = fx; s2y[0] = fy; s2z[0] = fz; }
    for (int s = 1; s < NP1; ++s) {
        float bestv = -1.f; int besti = 0;
        const f32x2 vfx = mk2(fx, fx), vfy = mk2(fy, fy), vfz = mk2(fz, fz);
#pragma unroll
        for (int k = 0; k < H; ++k) {
            const f32x2 dx = vx[k] - vfx;
            const f32x2 dy = vy[k] - vfy;
            const f32x2 dz = vz[k] - vfz;
            const f32x2 d  = (dx*dx + dy*dy) + dz*dz;   // per-element IEEE, contract off
            const float nd0 = fminf(vd[k].x, d.x);
            const float nd1 = fminf(vd[k].y, d.y);
            vd[k].x = nd0; vd[k].y = nd1;
            if (nd0 > bestv) { bestv = nd0; besti = t + (2*k)   * BLOCK; }
            if (nd1 > bestv) { bestv = nd1; besti = t + (2*k+1) * BLOCK; }
        }
        const float wm = wave_max_bcast(bestv);
        const unsigned cand = (bestv == wm) ? (unsigned)besti : 0xffffffffu;
        const unsigned wi = wave_min_bcast(cand);
        const int par = s & 1;
        if (lane == 0)
            wslot[par][wv] = ((unsigned long long)__float_as_uint(wm) << 32)
                           | (unsigned)(~wi);
        __syncthreads();
        unsigned long long pa = wslot[par][0];
#pragma unroll
        for (int w = 1; w < NW; ++w) {
            const unsigned long long pb = wslot[par][w];
            pa = (pb > pa) ? pb : pa;
        }
        const int far = (int)(~(unsigned)pa);
        fx = sx[far]; fy = sy[far]; fz = sz[far];
        if (t == 0) { s2x[s] = fx; s2y[s] = fy; s2z[s] = fz; }
    }
    __syncthreads();
    for (int i = t; i < NP1; i += BLOCK) {
        out1[((size_t)b*NP1 + i)*3 + 0] = s2x[i];
        out1[((size_t)b*NP1 + i)*3 + 1] = s2y[i];
        out1[((size_t)b*NP1 + i)*3 + 2] = s2z[i];
    }
}

// ---- inline ball-query scan: ONE wave scans one query, indices -> LDS -----
template<int N, int K>
__device__ __forceinline__ void ballq_scan_lds(const float* __restrict__ xb,
                                               const float qx, const float qy,
                                               const float qz, const float r2,
                                               int* __restrict__ sidx,
                                               const int lane)
{
#pragma clang fp contract(off)
    int base = 0, first = -1;
    for (int c = 0; c < N; c += 64) {
        const int i = c + lane;
        const float dx = xb[i*3+0]-qx, dy = xb[i*3+1]-qy, dz = xb[i*3+2]-qz;
        const float d = (dx*dx + dy*dy) + dz*dz;
        const bool hit = !(d > r2);
        const unsigned long long m = __ballot(hit);
        if (first < 0 && m) first = c + __builtin_ctzll(m);
        const int pos = base + __popcll(m & ((1ull << lane) - 1ull));
        if (hit && pos < K) sidx[pos] = i;
        base += __popcll(m);
        if (base >= K) break;
    }
    if (base < K && lane >= base && lane < K) sidx[lane] = first;
}

// 8 packed FMAs against 16 contiguous transposed weights (bit-identical).
__device__ __forceinline__ void fma16pk(f32x2 (&acc)[8], const float f,
                                        const float* __restrict__ wrow)
{
    const float4 w0 = ((const float4*)wrow)[0];
    const float4 w1 = ((const float4*)wrow)[1];
    const float4 w2 = ((const float4*)wrow)[2];
    const float4 w3 = ((const float4*)wrow)[3];
    const f32x2 ff = mk2(f, f);
    acc[0] += ff * mk2(w0.x, w0.y);
    acc[1] += ff * mk2(w0.z, w0.w);
    acc[2] += ff * mk2(w1.x, w1.y);
    acc[3] += ff * mk2(w1.z, w1.w);
    acc[4] += ff * mk2(w2.x, w2.y);
    acc[5] += ff * mk2(w2.z, w2.w);
    acc[6] += ff * mk2(w3.x, w3.y);
    acc[7] += ff * mk2(w3.z, w3.w);
}

__device__ __forceinline__ float pool_half(float v)
{
    v = fmaxf(v, __shfl_xor(v, 1));
    v = fmaxf(v, __shfl_xor(v, 2));
    v = fmaxf(v, __shfl_xor(v, 4));
    v = fmaxf(v, __shfl_xor(v, 8));
    v = fmaxf(v, __shfl_xor(v, 16));
    return v;
}
__device__ __forceinline__ float pool_full(float v)
{
    v = pool_half(v);
    return fmaxf(v, __shfl_xor(v, 32));
}

// ---------------------------------------------------------------------------
// K2: blocks [0,BATCH) = single-wave FPS stage 2 (unchanged R17);
// blocks [BATCH,...) = SA1 (+inline ball query), unchanged.
// ---------------------------------------------------------------------------
template<int NP1, int NP2, int BLOCK>
__global__ __launch_bounds__(BLOCK)
void fps2_sa1(const float* __restrict__ xyz, const float* __restrict__ l1xyz,
              float* __restrict__ out2, const float r2,
              const float* __restrict__ Wt0, const float* __restrict__ B0,
              const float* __restrict__ Wt1, const float* __restrict__ B1,
              const float* __restrict__ Wt2, const float* __restrict__ B2,
              float* __restrict__ out)
{
#pragma clang fp contract(off)
    __shared__ __align__(16) char smem[16640];
    const int tid = threadIdx.x, lane = tid & 63;
    if ((int)blockIdx.x < BATCH) {
        if (tid >= 64) return;                     // single wave does stage 2
        constexpr int P2 = NP1 / 64;               // 8 pts per lane (blocked)
        float* s2x = (float*)smem;                 // [NP1]
        float* s2y = s2x + NP1;
        float* s2z = s2y + NP1;
        float* o2x = s2z + NP1;                    // [NP2]
        float* o2y = o2x + NP2;
        float* o2z = o2y + NP2;
        const int b = blockIdx.x;
        const float* l1b = l1xyz + (size_t)b * NP1 * 3;
        float px[P2], py[P2], pz[P2], dist[P2];
#pragma unroll
        for (int j = 0; j < P2; ++j) {
            const int i = lane * P2 + j;
            const float x = l1b[i*3+0], y = l1b[i*3+1], z = l1b[i*3+2];
            s2x[i] = x; s2y[i] = y; s2z[i] = z;
            px[j] = x; py[j] = y; pz[j] = z;
            dist[j] = 1e10f;
        }
        float fx = l1b[0], fy = l1b[1], fz = l1b[2];
        if (lane == 0) { o2x[0] = fx; o2y[0] = fy; o2z[0] = fz; }
        for (int s = 1; s < NP2; ++s) {
            float bestv = -1.f; int besti = 0;
#pragma unroll
            for (int j = 0; j < P2; ++j) {
                const float dx = px[j]-fx, dy = py[j]-fy, dz = pz[j]-fz;
                const float d = (dx*dx + dy*dy) + dz*dz;
                const float nd = fminf(dist[j], d);
                dist[j] = nd;
                if (nd > bestv) { bestv = nd; besti = lane * P2 + j; }
            }
            const float wm = wave_max_bcast(bestv);
            const unsigned cand = (bestv == wm) ? (unsigned)besti : 0xffffffffu;
            const unsigned wi = wave_min_bcast(cand);
            fx = s2x[wi]; fy = s2y[wi]; fz = s2z[wi];   // same-wave LDS broadcast
            if (lane == 0) { o2x[s] = fx; o2y[s] = fy; o2z[s] = fz; }
        }
        for (int i = lane; i < NP2; i += 64) {
            out2[((size_t)b*NP2 + i)*3 + 0] = o2x[i];
            out2[((size_t)b*NP2 + i)*3 + 1] = o2y[i];
            out2[((size_t)b*NP2 + i)*3 + 2] = o2z[i];
        }
        return;
    }
    // ---------------- SA1 (+inline ball query), unchanged ----------------
    float (*buf)[64] = (float(*)[64])smem;         // [64][64]
    int* sidx = (int*)(smem + 16384);              // [64]
    const int wave = __builtin_amdgcn_readfirstlane(tid >> 6);
    const int row0 = (blockIdx.x - BATCH) * 64;
    const int g0 = row0 >> 5;
    const int b = g0 >> 9;
    const float* xb = xyz + (size_t)b * 4096 * 3;
    if (wave < 2) {
        const int g = g0 + wave;
        ballq_scan_lds<4096, 32>(xb,
            l1xyz[(size_t)g*3 + 0], l1xyz[(size_t)g*3 + 1], l1xyz[(size_t)g*3 + 2],
            r2, sidx + wave*32, lane);
    }
    __syncthreads();
    const int g = g0 + (lane >> 5);
    const int i = sidx[lane];
    const float* p = xb + (size_t)i * 3;
    const float f0 = p[0] - l1xyz[(size_t)g*3 + 0];
    const float f1 = p[1] - l1xyz[(size_t)g*3 + 1];
    const float f2 = p[2] - l1xyz[(size_t)g*3 + 2];
    const int oc0 = wave * 16;
    f32x2 aL[8], aH[8];
#pragma unroll
    for (int j = 0; j < 16; ++j) {
        const float v = B0[oc0+j] + f0*Wt0[0*64+oc0+j] + f1*Wt0[1*64+oc0+j] + f2*Wt0[2*64+oc0+j];
        buf[oc0+j][lane] = fmaxf(v, 0.f);
    }
    __syncthreads();
#pragma unroll
    for (int k = 0; k < 8; ++k) aL[k] = mk2(B1[oc0+2*k], B1[oc0+2*k+1]);
#pragma unroll 4
    for (int ci = 0; ci < 64; ++ci)
        fma16pk(aL, buf[ci][lane], Wt1 + ci*64 + oc0);
    __syncthreads();
#pragma unroll
    for (int k = 0; k < 8; ++k) {
        buf[oc0+2*k][lane]   = fmaxf(aL[k].x, 0.f);
        buf[oc0+2*k+1][lane] = fmaxf(aL[k].y, 0.f);
    }
    __syncthreads();
#pragma unroll
    for (int k = 0; k < 8; ++k) {
        aL[k] = mk2(B2[oc0+2*k], B2[oc0+2*k+1]);
        aH[k] = mk2(B2[64+oc0+2*k], B2[64+oc0+2*k+1]);
    }
#pragma unroll 2
    for (int ci = 0; ci < 64; ++ci) {
        const float f = buf[ci][lane];
        fma16pk(aL, f, Wt2 + ci*128 + oc0);
        fma16pk(aH, f, Wt2 + ci*128 + 64 + oc0);
    }
#pragma unroll
    for (int k = 0; k < 8; ++k) {
        const float v0 = pool_half(fmaxf(aL[k].x, 0.f));
        const float v1 = pool_half(fmaxf(aL[k].y, 0.f));
        const float w0 = pool_half(fmaxf(aH[k].x, 0.f));
        const float w1 = pool_half(fmaxf(aH[k].y, 0.f));
        if ((lane & 31) == 0) {
            const size_t orow = (size_t)((row0 + lane) >> 5) * 128;
            out[orow + oc0 + 2*k]       = v0;
            out[orow + oc0 + 2*k + 1]   = v1;
            out[orow + 64 + oc0 + 2*k]     = w0;
            out[orow + 64 + oc0 + 2*k + 1] = w1;
        }
    }
}

// ---------------------------------------------------------------------------
// SA2 fused + inline ball query + SA3-L1 + SA3-L2 epilogues. (unchanged R15)
// ---------------------------------------------------------------------------
__global__ __launch_bounds__(256)
void sa2_fused(const float* __restrict__ l1xyz, const float* __restrict__ l1pts,
               const float* __restrict__ nxyz, const float r2,
               const float* __restrict__ Wt0, const float* __restrict__ B0,
               const float* __restrict__ Wt1, const float* __restrict__ B1,
               const float* __restrict__ Wt2, const float* __restrict__ B2,
               const float* __restrict__ Wt30, const float* __restrict__ B30,
               const float* __restrict__ Wt31, const float* __restrict__ B31,
               float* __restrict__ outH2)
{
    __shared__ float buf[128][64];
    __shared__ float pool[256];
    __shared__ float h1s[256];
    __shared__ int sidx[64];
    const int tid = threadIdx.x, lane = tid & 63;
    const int wave = __builtin_amdgcn_readfirstlane(tid >> 6);
    const int gblk = blockIdx.x;
    const int b = gblk >> 7;
    const float cx = nxyz[(size_t)gblk*3 + 0];
    const float cy = nxyz[(size_t)gblk*3 + 1];
    const float cz = nxyz[(size_t)gblk*3 + 2];
    const float* xb = l1xyz + (size_t)b * 512 * 3;
    if (wave == 0)
        ballq_scan_lds<512, 64>(xb, cx, cy, cz, r2, sidx, lane);
    __syncthreads();
    const int myi = sidx[lane];
    const float* pc = xb + (size_t)myi * 3;
    const float f0 = pc[0] - cx;
    const float f1 = pc[1] - cy;
    const float f2 = pc[2] - cz;
    for (int r = wave; r < 64; r += 4) {
        const int i2 = sidx[r];
        const float* src = l1pts + ((size_t)b*512 + i2) * 128;
        buf[lane][r ^ lane]    = src[lane];
        buf[lane+64][r ^ lane] = src[lane + 64];
    }
    __syncthreads();
    const int oc0 = wave * 16;
    f32x2 aL[8], aH[8];
#pragma unroll
    for (int k = 0; k < 8; ++k) {
        const int j0 = oc0 + 2*k, j1 = oc0 + 2*k + 1;
        aL[k] = mk2(B0[j0]    + f0*Wt0[j0]     + f1*Wt0[128+j0]    + f2*Wt0[256+j0],
                    B0[j1]    + f0*Wt0[j1]     + f1*Wt0[128+j1]    + f2*Wt0[256+j1]);
        aH[k] = mk2(B0[64+j0] + f0*Wt0[64+j0]  + f1*Wt0[192+j0]    + f2*Wt0[320+j0],
                    B0[64+j1] + f0*Wt0[64+j1]  + f1*Wt0[192+j1]    + f2*Wt0[320+j1]);
    }
#pragma unroll 2
    for (int ci = 0; ci < 128; ++ci) {
        const float f = buf[ci][lane ^ (ci & 63)];
        const float* wp = Wt0 + (size_t)(ci+3)*128;
        fma16pk(aL, f, wp + oc0);
        fma16pk(aH, f, wp + 64 + oc0);
    }
    __syncthreads();
#pragma unroll
    for (int k = 0; k < 8; ++k) {
        buf[oc0+2*k][lane]      = fmaxf(aL[k].x, 0.f);
        buf[oc0+2*k+1][lane]    = fmaxf(aL[k].y, 0.f);
        buf[64+oc0+2*k][lane]   = fmaxf(aH[k].x, 0.f);
        buf[64+oc0+2*k+1][lane] = fmaxf(aH[k].y, 0.f);
    }
    __syncthreads();
#pragma unroll
    for (int k = 0; k < 8; ++k) {
        aL[k] = mk2(B1[oc0+2*k], B1[oc0+2*k+1]);
        aH[k] = mk2(B1[64+oc0+2*k], B1[64+oc0+2*k+1]);
    }
#pragma unroll 2
    for (int ci = 0; ci < 128; ++ci) {
        const float f = buf[ci][lane];
        const float* wp = Wt1 + (size_t)ci*128;
        fma16pk(aL, f, wp + oc0);
        fma16pk(aH, f, wp + 64 + oc0);
    }
    __syncthreads();
#pragma unroll
    for (int k = 0; k < 8; ++k) {
        buf[oc0+2*k][lane]      = fmaxf(aL[k].x, 0.f);
        buf[oc0+2*k+1][lane]    = fmaxf(aL[k].y, 0.f);
        buf[64+oc0+2*k][lane]   = fmaxf(aH[k].x, 0.f);
        buf[64+oc0+2*k+1][lane] = fmaxf(aH[k].y, 0.f);
    }
    __syncthreads();
    for (int half = 0; half < 2; ++half) {
        const int oc = half*128 + oc0;
#pragma unroll
        for (int k = 0; k < 8; ++k) {
            aL[k] = mk2(B2[oc+2*k], B2[oc+2*k+1]);
            aH[k] = mk2(B2[64+oc+2*k], B2[64+oc+2*k+1]);
        }
#pragma unroll 2
        for (int ci = 0; ci < 128; ++ci) {
            const float f = buf[ci][lane];
            const float* wp = Wt2 + (size_t)ci*256;
            fma16pk(aL, f, wp + oc);
            fma16pk(aH, f, wp + 64 + oc);
        }
#pragma unroll
        for (int k = 0; k < 8; ++k) {
            const float v0 = pool_full(fmaxf(aL[k].x, 0.f));
            const float v1 = pool_full(fmaxf(aL[k].y, 0.f));
            const float w0 = pool_full(fmaxf(aH[k].x, 0.f));
            const float w1 = pool_full(fmaxf(aH[k].y, 0.f));
            if (lane == 0) {
                pool[oc + 2*k]        = v0;
                pool[oc + 2*k + 1]    = v1;
                pool[64 + oc + 2*k]   = w0;
                pool[64 + oc + 2*k+1] = w1;
            }
        }
    }
    __syncthreads();
    {
        float acc = B30[tid] + cx*Wt30[0*256+tid] + cy*Wt30[1*256+tid] + cz*Wt30[2*256+tid];
#pragma unroll 8
        for (int ci = 0; ci < 256; ++ci)
            acc += pool[ci] * Wt30[(size_t)(ci+3)*256 + tid];
        h1s[tid] = fmaxf(acc, 0.f);
    }
    __syncthreads();
    {
        float a0 = B31[tid], a1 = B31[256 + tid];
#pragma unroll 8
        for (int ci = 0; ci < 256; ++ci) {
            const float f = h1s[ci];
            a0 += f * Wt31[(size_t)ci*512 + tid];
            a1 += f * Wt31[(size_t)ci*512 + 256 + tid];
        }
        outH2[(size_t)gblk*512 + tid]       = fmaxf(a0, 0.f);
        outH2[(size_t)gblk*512 + 256 + tid] = fmaxf(a1, 0.f);
    }
}

// ---------------------------------------------------------------------------
// SA3 GEMM layer (<512,1024,POOL>), packed-FMA accumulators. (unchanged)
// ---------------------------------------------------------------------------
template<int CIN, int COUT, bool CONCAT3, bool POOL>
__global__ __launch_bounds__(256)
void mlp_gemm_kernel(const float* __restrict__ inA, const float* __restrict__ inB,
                     const float* __restrict__ Wt, const float* __restrict__ Bb,
                     float* __restrict__ out)
{
    __shared__ float featS[128][64];
    const int tid = threadIdx.x, lane = tid & 63;
    const int wave = __builtin_amdgcn_readfirstlane(tid >> 6);
    const int row0 = blockIdx.x * 64;
    const int oc0 = blockIdx.y * 64 + wave * 16;
    f32x2 acc[8];
#pragma unroll
    for (int k = 0; k < 8; ++k) acc[k] = mk2(Bb[oc0+2*k], Bb[oc0+2*k+1]);
    for (int c0 = 0; c0 < CIN; c0 += 128) {
        const int csz = (CIN - c0 < 128) ? (CIN - c0) : 128;
        __syncthreads();
        for (int r = wave; r < 64; r += 4) {
            const int row = row0 + r;
            for (int cl = lane; cl < csz; cl += 64) {
                const int cig = c0 + cl;
                float v;
                if (CONCAT3)
                    v = (cig < 3) ? inA[(size_t)row*3 + cig]
                                  : inB[(size_t)row*(CIN-3) + (cig - 3)];
                else
                    v = inA[(size_t)row*CIN + cig];
                featS[cl][r ^ (cl & 63)] = v;
            }
        }
        __syncthreads();
        if (csz == 128) {
#pragma unroll 4
            for (int ci = 0; ci < 128; ++ci)
                fma16pk(acc, featS[ci][lane ^ (ci & 63)], Wt + (size_t)(c0+ci)*COUT + oc0);
        } else {
            for (int ci = 0; ci < csz; ++ci)
                fma16pk(acc, featS[ci][lane ^ (ci & 63)], Wt + (size_t)(c0+ci)*COUT + oc0);
        }
    }
    if (POOL) {
#pragma unroll
        for (int k = 0; k < 8; ++k) {
            const float v0 = pool_full(fmaxf(acc[k].x, 0.f));
            const float v1 = pool_full(fmaxf(acc[k].y, 0.f));
            if (lane == 0) {
                out[(size_t)blockIdx.x * COUT + oc0 + 2*k]     = v0;
                out[(size_t)blockIdx.x * COUT + oc0 + 2*k + 1] = v1;
            }
        }
    } else {
        float4 o0, o1, o2, o3;
        o0.x=fmaxf(acc[0].x,0.f); o0.y=fmaxf(acc[0].y,0.f); o0.z=fmaxf(acc[1].x,0.f); o0.w=fmaxf(acc[1].y,0.f);
        o1.x=fmaxf(acc[2].x,0.f); o1.y=fmaxf(acc[2].y,0.f); o1.z=fmaxf(acc[3].x,0.f); o1.w=fmaxf(acc[3].y,0.f);
        o2.x=fmaxf(acc[4].x,0.f); o2.y=fmaxf(acc[4].y,0.f); o2.z=fmaxf(acc[5].x,0.f); o2.w=fmaxf(acc[5].y,0.f);
        o3.x=fmaxf(acc[6].x,0.f); o3.y=fmaxf(acc[6].y,0.f); o3.z=fmaxf(acc[7].x,0.f); o3.w=fmaxf(acc[7].y,0.f);
        float4* op = (float4*)(out + (size_t)(row0 + lane)*COUT + oc0);
        op[0]=o0; op[1]=o1; op[2]=o2; op[3]=o3;
    }
}

// y[b][o] = fb[o] + max(pmax[2b], pmax[2b+1]) . fw[o]; one wave per output
__global__ __launch_bounds__(256)
void fc_kernel(const float* __restrict__ pmax, const float* __restrict__ fw,
               const float* __restrict__ fb, float* __restrict__ y)
{
    const int gw = (blockIdx.x * 256 + threadIdx.x) >> 6;
    const int lane = threadIdx.x & 63;
    const int b = gw >> 10, o = gw & 1023;
    const float4* g0 = (const float4*)(pmax + (size_t)(2*b) * 1024);
    const float4* g1 = (const float4*)(pmax + (size_t)(2*b+1) * 1024);
    const float4* wv = (const float4*)(fw + (size_t)o * 1024);
    float acc = 0.f;
#pragma unroll
    for (int r = 0; r < 4; ++r) {
        const float4 a = g0[lane + r*64];
        const float4 c = g1[lane + r*64];
        const float4 w = wv[lane + r*64];
        acc += fmaxf(a.x,c.x)*w.x + fmaxf(a.y,c.y)*w.y
             + fmaxf(a.z,c.z)*w.z + fmaxf(a.w,c.w)*w.w;
    }
#pragma unroll
    for (int m = 32; m >= 1; m >>= 1) acc += __shfl_xor(acc, m);
    if (lane == 0) y[gw] = acc + fb[o];
}

extern "C" void kernel_launch(void* const* d_in, const int* in_sizes, int n_in,
                              void* d_out, int out_size, void* d_ws, size_t ws_size,
                              hipStream_t stream)
{
    (void)in_sizes; (void)n_in; (void)out_size; (void)ws_size;
    const float* x   = (const float*)d_in[0];
    const float* s1w0 = (const float*)d_in[1];  const float* s1b0 = (const float*)d_in[2];
    const float* s1w1 = (const float*)d_in[3];  const float* s1b1 = (const float*)d_in[4];
    const float* s1w2 = (const float*)d_in[5];  const float* s1b2 = (const float*)d_in[6];
    const float* s2w0 = (const float*)d_in[7];  const float* s2b0 = (const float*)d_in[8];
    const float* s2w1 = (const float*)d_in[9];  const float* s2b1 = (const float*)d_in[10];
    const float* s2w2 = (const float*)d_in[11]; const float* s2b2 = (const float*)d_in[12];
    const float* s3w0 = (const float*)d_in[13]; const float* s3b0 = (const float*)d_in[14];
    const float* s3w1 = (const float*)d_in[15]; const float* s3b1 = (const float*)d_in[16];
    const float* s3w2 = (const float*)d_in[17]; const float* s3b2 = (const float*)d_in[18];
    const float* fw  = (const float*)d_in[19]; const float* fb  = (const float*)d_in[20];
    float* y = (float*)d_out;

    char* ws = (char*)d_ws;
    float* l1_xyz = (float*)(ws + 0);          // 16*512*3
    float* l1_pts = (float*)(ws + 1146880);    // 16*512*128
    float* l2_xyz = (float*)(ws + 5341184);    // 16*128*3
    float* h2     = (float*)(ws + 10084352);   // 2048*512
    float* pmax   = (float*)(ws + 14278656);   // 32*1024 partial maxes
    float* wt1_0  = (float*)(ws + 14409728);   // [3][64]
    float* wt1_1  = (float*)(ws + 14410496);   // [64][64]
    float* wt1_2  = (float*)(ws + 14426880);   // [64][128]
    float* wt2_0  = (float*)(ws + 14459648);   // [131][128]
    float* wt2_1  = (float*)(ws + 14526720);   // [128][128]
    float* wt2_2  = (float*)(ws + 14592256);   // [128][256]
    float* wt3_0  = (float*)(ws + 14723328);   // [259][256]
    float* wt3_1  = (float*)(ws + 14988544);   // [256][512]
    float* wt3_2  = (float*)(ws + 15512832);   // [512][1024]

    const float r2_1 = (float)(0.2 * 0.2);
    const float r2_2 = (float)(0.4 * 0.4);

    // K1: FPS stage 1 (16 blocks) + all weight transposes (3126 blocks)
    fps1_fused<4096, 512, 256><<<BATCH + 3126, 256, 0, stream>>>(
        x, l1_xyz,
        s1w0, wt1_0, s1w1, wt1_1, s1w2, wt1_2,
        s2w0, wt2_0, s2w1, wt2_1, s2w2, wt2_2,
        s3w0, wt3_0, s3w1, wt3_1, s3w2, wt3_2);
    // K2: single-wave FPS stage 2 (16 blocks) concurrent with SA1 (4096 blocks)
    fps2_sa1<512, 128, 256><<<BATCH + (BATCH*512*32)/64, 256, 0, stream>>>(
        x, l1_xyz, l2_xyz, r2_1,
        wt1_0, s1b0, wt1_1, s1b1, wt1_2, s1b2, l1_pts);
    sa2_fused<<<BATCH*128, 256, 0, stream>>>(l1_xyz, l1_pts, l2_xyz, r2_2,
        wt2_0, s2b0, wt2_1, s2b1, wt2_2, s2b2,
        wt3_0, s3b0, wt3_1, s3b1, h2);
    mlp_gemm_kernel<512, 1024, false, true ><<<dim3(32, 16), 256, 0, stream>>>(h2, nullptr, wt3_2, s3b2, pmax);
    fc_kernel<<<(BATCH*1024)/4, 256, 0, stream>>>(pmax, fw, fb, y);
}